// Round 1
// baseline (182.701 us; speedup 1.0000x reference)
//
#include <hip/hip_runtime.h>
#include <hip/hip_bf16.h>
#include <cstdint>
#include <cstddef>

typedef __attribute__((ext_vector_type(8))) short short8;
typedef __attribute__((ext_vector_type(4))) float f32x4;

#define BM 128
#define BN 128
#define BK 64
#define NC 16   // candidate pool per row (true top-11 needed; bf16 rank noise << 5)

__device__ __forceinline__ void gload_lds16(const void* g, void* l) {
  typedef const __attribute__((address_space(1))) void* gp_t;
  typedef __attribute__((address_space(3))) void* lp_t;
  __builtin_amdgcn_global_load_lds((gp_t)(unsigned long long)(uintptr_t)g,
                                   (lp_t)(unsigned int)(unsigned long long)(uintptr_t)l,
                                   16, 0, 0);
}

// ---------- kernel 1: bf16 cast of feats + fp32 row squared-norms ----------
__global__ __launch_bounds__(256)
void prep_kernel(const float* __restrict__ zi, const float* __restrict__ zj,
                 unsigned short* __restrict__ fb, float* __restrict__ sq,
                 int n, int d) {
  __shared__ float wred[4];
  const int row = blockIdx.x;
  const int t = threadIdx.x, lane = t & 63, wave = t >> 6;
  const float* src = (row < n) ? (zi + (size_t)row * d) : (zj + (size_t)(row - n) * d);
  float s = 0.f;
  for (int c = t; c < d; c += 256) {
    float v = src[c];
    s += v * v;
    __hip_bfloat16 h = __float2bfloat16(v);
    fb[(size_t)row * d + c] = *reinterpret_cast<const unsigned short*>(&h);
  }
#pragma unroll
  for (int o = 32; o; o >>= 1) s += __shfl_xor(s, o, 64);
  if (lane == 0) wred[wave] = s;
  __syncthreads();
  if (t == 0) sq[row] = ((wred[0] + wred[1]) + wred[2]) + wred[3];
}

// ---------- kernel 2: bf16 MFMA GEMM (f f^T) -> pd matrix (diag = +inf) ----------
__global__ __launch_bounds__(256)
void gemm_pd_kernel(const unsigned short* __restrict__ fb,
                    const float* __restrict__ sq,
                    float* __restrict__ pd, int b, int d) {
  __shared__ unsigned short smA[BM * BK];
  __shared__ unsigned short smB[BN * BK];
  const int t = threadIdx.x;
  const int lane = t & 63;
  const int wave = t >> 6;
  const int wr = wave >> 1, wc = wave & 1;
  const int rowBase = blockIdx.y * BM;
  const int colBase = blockIdx.x * BN;
  const int l15 = lane & 15, l4 = lane >> 4;

  f32x4 acc[4][4] = {};

  for (int kt = 0; kt < d; kt += BK) {
#pragma unroll
    for (int it = 0; it < 4; ++it) {
      const int c = it * 256 + t;      // 1024 16B-chunks per 128x64 tile
      const int r = c >> 3;
      const int kk = (c & 7) * 8;
      gload_lds16(fb + (size_t)(rowBase + r) * d + kt + kk, (char*)smA + c * 16);
      gload_lds16(fb + (size_t)(colBase + r) * d + kt + kk, (char*)smB + c * 16);
    }
    __syncthreads();
#pragma unroll
    for (int ks = 0; ks < 2; ++ks) {
      short8 af[4], bfr[4];
#pragma unroll
      for (int m = 0; m < 4; ++m)
        af[m] = *(const short8*)&smA[(wr * 64 + m * 16 + l15) * BK + ks * 32 + l4 * 8];
#pragma unroll
      for (int nn = 0; nn < 4; ++nn)
        bfr[nn] = *(const short8*)&smB[(wc * 64 + nn * 16 + l15) * BK + ks * 32 + l4 * 8];
#pragma unroll
      for (int m = 0; m < 4; ++m)
#pragma unroll
        for (int nn = 0; nn < 4; ++nn)
          acc[m][nn] = __builtin_amdgcn_mfma_f32_16x16x32_bf16(af[m], bfr[nn], acc[m][nn], 0, 0, 0);
    }
    __syncthreads();
  }

  const float INFV = __builtin_inff();
#pragma unroll
  for (int m = 0; m < 4; ++m) {
    const int gr0 = rowBase + wr * 64 + m * 16 + l4 * 4;
#pragma unroll
    for (int nn = 0; nn < 4; ++nn) {
      const int gc = colBase + wc * 64 + nn * 16 + l15;
      const float sqc = sq[gc];
#pragma unroll
      for (int rg = 0; rg < 4; ++rg) {
        const int gr = gr0 + rg;
        float d2 = sq[gr] + sqc - 2.0f * acc[m][nn][rg];
        float p = sqrtf(fmaxf(d2, 0.0f));
        pd[(size_t)gr * b + gc] = (gr == gc) ? INFV : p;
      }
    }
  }
}

// ---------- kernel 3: per-row top-16 select, exact fp32 re-rank, loss ----------
__global__ __launch_bounds__(256)
void topk_loss_kernel(const float* __restrict__ pd,
                      const float* __restrict__ zi, const float* __restrict__ zj,
                      const float* __restrict__ pi, const float* __restrict__ pj,
                      const int* __restrict__ labels,
                      const float* __restrict__ sq,
                      float* __restrict__ rowsum,
                      int n, int d, int C, int b) {
  __shared__ float svals[4096];
  __shared__ float frow[512];
  __shared__ float prow[128];
  __shared__ unsigned long long wred64[4];
  __shared__ float wredf[4];
  __shared__ int cidx[NC];
  __shared__ float cpd[NC];
  __shared__ int ord[NC];

  const int row = blockIdx.x;
  const int t = threadIdx.x, lane = t & 63, wave = t >> 6;

  for (int c = t; c < b; c += 256) svals[c] = pd[(size_t)row * b + c];
  __syncthreads();

  // 16 rounds of block-wide argmin (packed value<<32|idx, ties -> lower idx)
  for (int r = 0; r < NC; ++r) {
    unsigned long long best = ~0ull;
    for (int c = t; c < b; c += 256) {
      unsigned long long p =
          (((unsigned long long)__float_as_uint(svals[c])) << 32) | (unsigned)c;
      if (p < best) best = p;
    }
#pragma unroll
    for (int o = 32; o; o >>= 1) {
      unsigned long long q = __shfl_xor(best, o, 64);
      if (q < best) best = q;
    }
    if (lane == 0) wred64[wave] = best;
    __syncthreads();
    if (t == 0) {
      unsigned long long mb = wred64[0];
      for (int wv = 1; wv < 4; ++wv) if (wred64[wv] < mb) mb = wred64[wv];
      int idx = (int)(unsigned)mb;
      cidx[r] = idx;
      svals[idx] = __builtin_inff();
    }
    __syncthreads();
  }

  // exact fp32 distances for the 16 candidates
  const float* fsrc = (row < n) ? (zi + (size_t)row * d) : (zj + (size_t)(row - n) * d);
  for (int c = t; c < d; c += 256) frow[c] = fsrc[c];
  __syncthreads();
  for (int k = 0; k < NC; ++k) {
    const int j = cidx[k];
    const float* g = (j < n) ? (zi + (size_t)j * d) : (zj + (size_t)(j - n) * d);
    float part = 0.f;
    for (int c = t; c < d; c += 256) part += frow[c] * g[c];
#pragma unroll
    for (int o = 32; o; o >>= 1) part += __shfl_xor(part, o, 64);
    if (lane == 0) wredf[wave] = part;
    __syncthreads();
    if (t == 0) {
      float dot = ((wredf[0] + wredf[1]) + wredf[2]) + wredf[3];
      float d2 = sq[row] + sq[j] - 2.0f * dot;
      cpd[k] = sqrtf(fmaxf(d2, 0.0f));
    }
    __syncthreads();
  }

  // sort 16 by (pd, idx) ascending — serial on t0, trivial
  if (t == 0) {
    for (int k = 0; k < NC; ++k) ord[k] = k;
    for (int a = 1; a < NC; ++a) {
      int oa = ord[a];
      float va = cpd[oa]; int ia = cidx[oa];
      int p = a - 1;
      while (p >= 0 && (cpd[ord[p]] > va || (cpd[ord[p]] == va && cidx[ord[p]] > ia))) {
        ord[p + 1] = ord[p]; --p;
      }
      ord[p + 1] = oa;
    }
  }
  __syncthreads();

  const float radius = cpd[ord[0]];   // == min_{j!=i} pd (reference sort[:,1], diag ~0)
  const float* psrc = (row < n) ? (pi + (size_t)row * C) : (pj + (size_t)(row - n) * C);
  for (int c = t; c < C; c += 256) prow[c] = psrc[c];
  __syncthreads();

  const int ri = (row < n) ? row : row - n;
  const int li = labels[ri];
  float total = 0.f;  // meaningful on t0 only
  for (int k = 0; k < 10; ++k) {
    const int j = cidx[ord[k]];
    const float* q = (j < n) ? (pi + (size_t)j * C) : (pj + (size_t)(j - n) * C);
    float part = 0.f;
    for (int c = t; c < C; c += 256) part += prow[c] * q[c];
#pragma unroll
    for (int o = 32; o; o >>= 1) part += __shfl_xor(part, o, 64);
    if (lane == 0) wredf[wave] = part;
    __syncthreads();
    if (t == 0) {
      float inner = ((wredf[0] + wredf[1]) + wredf[2]) + wredf[3];
      float pdj = cpd[ord[k]];
      float w = 1.0f - fminf(fmaxf((pdj - radius) / radius, 0.0f), 1.0f);
      int rj = (j < n) ? j : j - n;
      int lj = labels[rj];
      if (li != -1 && lj != -1 && li == lj && ri != rj) total += w * inner;
    }
    __syncthreads();
  }
  if (t == 0) rowsum[row] = total;
}

// ---------- kernel 4: deterministic final reduce ----------
__global__ __launch_bounds__(256)
void final_reduce_kernel(const float* __restrict__ rowsum, float* __restrict__ out, int b) {
  __shared__ float wredf[4];
  const int t = threadIdx.x, lane = t & 63, wave = t >> 6;
  float s = 0.f;
  for (int c = t; c < b; c += 256) s += rowsum[c];
#pragma unroll
  for (int o = 32; o; o >>= 1) s += __shfl_xor(s, o, 64);
  if (lane == 0) wredf[wave] = s;
  __syncthreads();
  if (t == 0) {
    float tot = ((wredf[0] + wredf[1]) + wredf[2]) + wredf[3];
    out[0] = tot / ((float)b * (float)b);
  }
}

extern "C" void kernel_launch(void* const* d_in, const int* in_sizes, int n_in,
                              void* d_out, int out_size, void* d_ws, size_t ws_size,
                              hipStream_t stream) {
  const float* zi = (const float*)d_in[0];
  const float* zj = (const float*)d_in[1];
  const float* pi = (const float*)d_in[2];
  const float* pj = (const float*)d_in[3];
  const int* labels = (const int*)d_in[4];

  const int n = in_sizes[4];          // 2048
  const int d = in_sizes[0] / n;      // 512
  const int C = in_sizes[2] / n;      // 128
  const int b = 2 * n;                // 4096

  char* ws = (char*)d_ws;
  size_t off = 0;
  unsigned short* fb = (unsigned short*)(ws + off);
  off += ((size_t)b * d * 2 + 255) & ~(size_t)255;
  float* sq = (float*)(ws + off);
  off += ((size_t)b * 4 + 255) & ~(size_t)255;
  float* rowsum = (float*)(ws + off);
  off += ((size_t)b * 4 + 255) & ~(size_t)255;
  float* pd = (float*)(ws + off);
  off += (size_t)b * b * 4;
  if (ws_size < off) return;  // workspace too small — bail rather than corrupt

  prep_kernel<<<b, 256, 0, stream>>>(zi, zj, fb, sq, n, d);
  dim3 grid(b / BN, b / BM);
  gemm_pd_kernel<<<grid, 256, 0, stream>>>(fb, sq, pd, b, d);
  topk_loss_kernel<<<b, 256, 0, stream>>>(pd, zi, zj, pi, pj, labels, sq, rowsum, n, d, C, b);
  final_reduce_kernel<<<1, 256, 0, stream>>>(rowsum, (float*)d_out, b);
}

// Round 2
// 153.560 us; speedup vs baseline: 1.1898x; 1.1898x over previous
//
#include <hip/hip_runtime.h>
#include <hip/hip_bf16.h>
#include <hip/hip_fp16.h>
#include <cstdint>
#include <cstddef>

typedef __attribute__((ext_vector_type(8))) short short8;
typedef __attribute__((ext_vector_type(4))) float f32x4;

#define BM 128
#define BN 128
#define BK 64
#define NC 16   // candidate pool per row (need true top-11; approx-rank noise margin = 5)

__device__ __forceinline__ void gload_lds16(const void* g, void* l) {
  typedef const __attribute__((address_space(1))) void* gp_t;
  typedef __attribute__((address_space(3))) void* lp_t;
  __builtin_amdgcn_global_load_lds((gp_t)(unsigned long long)(uintptr_t)g,
                                   (lp_t)(unsigned int)(unsigned long long)(uintptr_t)l,
                                   16, 0, 0);
}

// ---------- kernel 1: bf16 cast of feats + fp32 row squared-norms ----------
__global__ __launch_bounds__(256)
void prep_kernel(const float* __restrict__ zi, const float* __restrict__ zj,
                 unsigned short* __restrict__ fb, float* __restrict__ sq,
                 int n, int d) {
  __shared__ float wred[4];
  const int row = blockIdx.x;
  const int t = threadIdx.x, lane = t & 63, wave = t >> 6;
  const float* src = (row < n) ? (zi + (size_t)row * d) : (zj + (size_t)(row - n) * d);
  float s = 0.f;
  for (int c = t; c < d; c += 256) {
    float v = src[c];
    s += v * v;
    __hip_bfloat16 h = __float2bfloat16(v);
    fb[(size_t)row * d + c] = *reinterpret_cast<const unsigned short*>(&h);
  }
#pragma unroll
  for (int o = 32; o; o >>= 1) s += __shfl_xor(s, o, 64);
  if (lane == 0) wred[wave] = s;
  __syncthreads();
  if (t == 0) sq[row] = ((wred[0] + wred[1]) + wred[2]) + wred[3];
}

// ---------- kernel 2: bf16 MFMA GEMM (f f^T) -> approx d^2 (fp16, diag=+inf) ----------
__global__ __launch_bounds__(256)
void gemm_pd_kernel(const unsigned short* __restrict__ fb,
                    const float* __restrict__ sq,
                    __half* __restrict__ pdh, int b, int d) {
  __shared__ unsigned short smA[BM * BK];
  __shared__ unsigned short smB[BN * BK];
  const int t = threadIdx.x;
  const int lane = t & 63;
  const int wave = t >> 6;
  const int wr = wave >> 1, wc = wave & 1;
  const int rowBase = blockIdx.y * BM;
  const int colBase = blockIdx.x * BN;
  const int l15 = lane & 15, l4 = lane >> 4;

  f32x4 acc[4][4] = {};

  for (int kt = 0; kt < d; kt += BK) {
#pragma unroll
    for (int it = 0; it < 4; ++it) {
      const int c = it * 256 + t;      // 1024 16B-chunks per 128x64 tile
      const int r = c >> 3;
      const int kk = (c & 7) * 8;
      gload_lds16(fb + (size_t)(rowBase + r) * d + kt + kk, (char*)smA + c * 16);
      gload_lds16(fb + (size_t)(colBase + r) * d + kt + kk, (char*)smB + c * 16);
    }
    __syncthreads();
#pragma unroll
    for (int ks = 0; ks < 2; ++ks) {
      short8 af[4], bfr[4];
#pragma unroll
      for (int m = 0; m < 4; ++m)
        af[m] = *(const short8*)&smA[(wr * 64 + m * 16 + l15) * BK + ks * 32 + l4 * 8];
#pragma unroll
      for (int nn = 0; nn < 4; ++nn)
        bfr[nn] = *(const short8*)&smB[(wc * 64 + nn * 16 + l15) * BK + ks * 32 + l4 * 8];
#pragma unroll
      for (int m = 0; m < 4; ++m)
#pragma unroll
        for (int nn = 0; nn < 4; ++nn)
          acc[m][nn] = __builtin_amdgcn_mfma_f32_16x16x32_bf16(af[m], bfr[nn], acc[m][nn], 0, 0, 0);
    }
    __syncthreads();
  }

  const float INFV = __builtin_inff();
#pragma unroll
  for (int m = 0; m < 4; ++m) {
    const int gr0 = rowBase + wr * 64 + m * 16 + l4 * 4;
#pragma unroll
    for (int nn = 0; nn < 4; ++nn) {
      const int gc = colBase + wc * 64 + nn * 16 + l15;
      const float sqc = sq[gc];
#pragma unroll
      for (int rg = 0; rg < 4; ++rg) {
        const int gr = gr0 + rg;
        float d2 = fmaxf(sq[gr] + sqc - 2.0f * acc[m][nn][rg], 0.0f);
        pdh[(size_t)gr * b + gc] = __float2half((gr == gc) ? INFV : d2);
      }
    }
  }
}

// ---------- kernel 3: reg-resident top-16 select, exact fp32 re-rank, loss ----------
__global__ __launch_bounds__(256)
void topk_loss_kernel(const __half* __restrict__ pdh,
                      const float* __restrict__ zi, const float* __restrict__ zj,
                      const float* __restrict__ pi, const float* __restrict__ pj,
                      const int* __restrict__ labels,
                      const float* __restrict__ sq,
                      float* __restrict__ rowsum,
                      int n, int d, int C, int b) {
  __shared__ float frow[512];
  __shared__ float prow[128];
  __shared__ unsigned long long wred64[4];
  __shared__ unsigned long long bcast;
  __shared__ int cidx[NC];
  __shared__ float cpd[NC];
  __shared__ int ord[NC];
  __shared__ float contrib[10];

  const int row = blockIdx.x;
  const int t = threadIdx.x, lane = t & 63, wave = t >> 6;

  // stage my feature row + prob row in LDS
  const float* fsrc = (row < n) ? (zi + (size_t)row * d) : (zj + (size_t)(row - n) * d);
  for (int c = t; c < d; c += 256) frow[c] = fsrc[c];
  const float* psrc = (row < n) ? (pi + (size_t)row * C) : (pj + (size_t)(row - n) * C);
  for (int c = t; c < C; c += 256) prow[c] = psrc[c];

  // load my 16 strided approx-d2 values into registers; local packed argmin
  const __half* rowp = pdh + (size_t)row * b;
  float v[16];
#pragma unroll
  for (int i = 0; i < 16; ++i) v[i] = __half2float(rowp[t + i * 256]);

  unsigned long long best =
      (((unsigned long long)__float_as_uint(v[0])) << 32) | (unsigned)t;
#pragma unroll
  for (int i = 1; i < 16; ++i) {
    unsigned long long p =
        (((unsigned long long)__float_as_uint(v[i])) << 32) | (unsigned)(t + i * 256);
    if (p < best) best = p;
  }

  // 16 rounds of block argmin over 256 thread-local minima
  for (int r = 0; r < NC; ++r) {
    unsigned long long m = best;
#pragma unroll
    for (int o = 32; o; o >>= 1) {
      unsigned long long q = __shfl_xor(m, o, 64);
      if (q < m) m = q;
    }
    if (lane == 0) wred64[wave] = m;
    __syncthreads();
    if (t == 0) {
      unsigned long long mb = wred64[0];
      for (int wv = 1; wv < 4; ++wv) if (wred64[wv] < mb) mb = wred64[wv];
      bcast = mb;
      cidx[r] = (int)(unsigned)mb;
    }
    __syncthreads();
    const int idx = (int)(unsigned)bcast;
    if ((idx & 255) == t) {   // owner: invalidate + recompute local min
#pragma unroll
      for (int i = 0; i < 16; ++i) if (t + i * 256 == idx) v[i] = __builtin_inff();
      unsigned long long nb =
          (((unsigned long long)__float_as_uint(v[0])) << 32) | (unsigned)t;
#pragma unroll
      for (int i = 1; i < 16; ++i) {
        unsigned long long p =
            (((unsigned long long)__float_as_uint(v[i])) << 32) | (unsigned)(t + i * 256);
        if (p < nb) nb = p;
      }
      best = nb;
    }
  }

  // exact fp32 distances for the 16 candidates — one candidate per wave
  for (int k = wave; k < NC; k += 4) {
    const int j = cidx[k];
    const float* g = (j < n) ? (zi + (size_t)j * d) : (zj + (size_t)(j - n) * d);
    float part = 0.f;
    for (int c = lane; c < d; c += 64) part += frow[c] * g[c];
#pragma unroll
    for (int o = 32; o; o >>= 1) part += __shfl_xor(part, o, 64);
    if (lane == 0) {
      float d2 = sq[row] + sq[j] - 2.0f * part;
      cpd[k] = sqrtf(fmaxf(d2, 0.0f));
    }
  }
  __syncthreads();

  // sort 16 by (pd, idx) ascending — serial on t0, trivial
  if (t == 0) {
    for (int k = 0; k < NC; ++k) ord[k] = k;
    for (int a = 1; a < NC; ++a) {
      int oa = ord[a];
      float va = cpd[oa]; int ia = cidx[oa];
      int p = a - 1;
      while (p >= 0 && (cpd[ord[p]] > va || (cpd[ord[p]] == va && cidx[ord[p]] > ia))) {
        ord[p + 1] = ord[p]; --p;
      }
      ord[p + 1] = oa;
    }
  }
  __syncthreads();

  const float radius = cpd[ord[0]];   // min_{j!=i} pd
  const int ri = (row < n) ? row : row - n;
  const int li = labels[ri];

  // 10 prob dots — one per wave
  for (int k = wave; k < 10; k += 4) {
    const int j = cidx[ord[k]];
    const float* q = (j < n) ? (pi + (size_t)j * C) : (pj + (size_t)(j - n) * C);
    float part = 0.f;
    for (int c = lane; c < C; c += 64) part += prow[c] * q[c];
#pragma unroll
    for (int o = 32; o; o >>= 1) part += __shfl_xor(part, o, 64);
    if (lane == 0) {
      const float pdj = cpd[ord[k]];
      const float w = 1.0f - fminf(fmaxf((pdj - radius) / radius, 0.0f), 1.0f);
      const int rj = (j < n) ? j : j - n;
      const int lj = labels[rj];
      contrib[k] = (li != -1 && lj != -1 && li == lj && ri != rj) ? w * part : 0.f;
    }
  }
  __syncthreads();
  if (t == 0) {
    float tot = 0.f;
    for (int k = 0; k < 10; ++k) tot += contrib[k];
    rowsum[row] = tot;
  }
}

// ---------- kernel 4: deterministic final reduce ----------
__global__ __launch_bounds__(256)
void final_reduce_kernel(const float* __restrict__ rowsum, float* __restrict__ out, int b) {
  __shared__ float wredf[4];
  const int t = threadIdx.x, lane = t & 63, wave = t >> 6;
  float s = 0.f;
  for (int c = t; c < b; c += 256) s += rowsum[c];
#pragma unroll
  for (int o = 32; o; o >>= 1) s += __shfl_xor(s, o, 64);
  if (lane == 0) wredf[wave] = s;
  __syncthreads();
  if (t == 0) {
    float tot = ((wredf[0] + wredf[1]) + wredf[2]) + wredf[3];
    out[0] = tot / ((float)b * (float)b);
  }
}

extern "C" void kernel_launch(void* const* d_in, const int* in_sizes, int n_in,
                              void* d_out, int out_size, void* d_ws, size_t ws_size,
                              hipStream_t stream) {
  const float* zi = (const float*)d_in[0];
  const float* zj = (const float*)d_in[1];
  const float* pi = (const float*)d_in[2];
  const float* pj = (const float*)d_in[3];
  const int* labels = (const int*)d_in[4];

  const int n = in_sizes[4];          // 2048
  const int d = in_sizes[0] / n;      // 512
  const int C = in_sizes[2] / n;      // 128
  const int b = 2 * n;                // 4096

  char* ws = (char*)d_ws;
  size_t off = 0;
  unsigned short* fb = (unsigned short*)(ws + off);
  off += ((size_t)b * d * 2 + 255) & ~(size_t)255;
  float* sq = (float*)(ws + off);
  off += ((size_t)b * 4 + 255) & ~(size_t)255;
  float* rowsum = (float*)(ws + off);
  off += ((size_t)b * 4 + 255) & ~(size_t)255;
  __half* pdh = (__half*)(ws + off);
  off += (size_t)b * b * 2;
  if (ws_size < off) return;  // workspace too small — bail rather than corrupt

  prep_kernel<<<b, 256, 0, stream>>>(zi, zj, fb, sq, n, d);
  dim3 grid(b / BN, b / BM);
  gemm_pd_kernel<<<grid, 256, 0, stream>>>(fb, sq, pdh, b, d);
  topk_loss_kernel<<<b, 256, 0, stream>>>(pdh, zi, zj, pi, pj, labels, sq, rowsum, n, d, C, b);
  final_reduce_kernel<<<1, 256, 0, stream>>>(rowsum, (float*)d_out, b);
}

// Round 3
// 73.336 us; speedup vs baseline: 2.4913x; 2.0939x over previous
//
#include <hip/hip_runtime.h>
#include <hip/hip_bf16.h>
#include <hip/hip_fp16.h>
#include <cstdint>
#include <cstddef>

typedef __attribute__((ext_vector_type(8))) short short8;
typedef __attribute__((ext_vector_type(8))) unsigned short ushort8;
typedef __attribute__((ext_vector_type(4))) float f32x4;

#define BM 128
#define BN 128
#define BK 64
#define NC 16   // candidate pool per row (need true top-11; approx-rank noise margin = 5)

__device__ __forceinline__ void gload_lds16(const void* g, void* l) {
  typedef const __attribute__((address_space(1))) void* gp_t;
  typedef __attribute__((address_space(3))) void* lp_t;
  __builtin_amdgcn_global_load_lds((gp_t)(unsigned long long)(uintptr_t)g,
                                   (lp_t)(unsigned int)(unsigned long long)(uintptr_t)l,
                                   16, 0, 0);
}

// ---------- kernel 1: bf16 cast of feats + fp32 row squared-norms ----------
__global__ __launch_bounds__(256)
void prep_kernel(const float* __restrict__ zi, const float* __restrict__ zj,
                 unsigned short* __restrict__ fb, float* __restrict__ sq,
                 int n, int d) {
  __shared__ float wred[4];
  const int row = blockIdx.x;
  const int t = threadIdx.x, lane = t & 63, wave = t >> 6;
  const float* src = (row < n) ? (zi + (size_t)row * d) : (zj + (size_t)(row - n) * d);
  float s = 0.f;
  for (int c = t; c < d; c += 256) {
    float v = src[c];
    s += v * v;
    __hip_bfloat16 h = __float2bfloat16(v);
    fb[(size_t)row * d + c] = *reinterpret_cast<const unsigned short*>(&h);
  }
#pragma unroll
  for (int o = 32; o; o >>= 1) s += __shfl_xor(s, o, 64);
  if (lane == 0) wred[wave] = s;
  __syncthreads();
  if (t == 0) sq[row] = ((wred[0] + wred[1]) + wred[2]) + wred[3];
}

// ---------- kernel 2: bf16 MFMA GEMM (f f^T) -> approx d^2 (fp16, diag=+inf) ----------
__global__ __launch_bounds__(256)
void gemm_pd_kernel(const unsigned short* __restrict__ fb,
                    const float* __restrict__ sq,
                    __half* __restrict__ pdh, int b, int d) {
  __shared__ unsigned short smA[BM * BK];
  __shared__ unsigned short smB[BN * BK];
  const int t = threadIdx.x;
  const int lane = t & 63;
  const int wave = t >> 6;
  const int wr = wave >> 1, wc = wave & 1;
  const int rowBase = blockIdx.y * BM;
  const int colBase = blockIdx.x * BN;
  const int l15 = lane & 15, l4 = lane >> 4;

  f32x4 acc[4][4] = {};

  for (int kt = 0; kt < d; kt += BK) {
#pragma unroll
    for (int it = 0; it < 4; ++it) {
      const int c = it * 256 + t;      // 1024 16B-chunks per 128x64 tile
      const int r = c >> 3;
      const int kk = (c & 7) * 8;
      gload_lds16(fb + (size_t)(rowBase + r) * d + kt + kk, (char*)smA + c * 16);
      gload_lds16(fb + (size_t)(colBase + r) * d + kt + kk, (char*)smB + c * 16);
    }
    __syncthreads();
#pragma unroll
    for (int ks = 0; ks < 2; ++ks) {
      short8 af[4], bfr[4];
#pragma unroll
      for (int m = 0; m < 4; ++m)
        af[m] = *(const short8*)&smA[(wr * 64 + m * 16 + l15) * BK + ks * 32 + l4 * 8];
#pragma unroll
      for (int nn = 0; nn < 4; ++nn)
        bfr[nn] = *(const short8*)&smB[(wc * 64 + nn * 16 + l15) * BK + ks * 32 + l4 * 8];
#pragma unroll
      for (int m = 0; m < 4; ++m)
#pragma unroll
        for (int nn = 0; nn < 4; ++nn)
          acc[m][nn] = __builtin_amdgcn_mfma_f32_16x16x32_bf16(af[m], bfr[nn], acc[m][nn], 0, 0, 0);
    }
    __syncthreads();
  }

  const float INFV = __builtin_inff();
#pragma unroll
  for (int m = 0; m < 4; ++m) {
    const int gr0 = rowBase + wr * 64 + m * 16 + l4 * 4;
#pragma unroll
    for (int nn = 0; nn < 4; ++nn) {
      const int gc = colBase + wc * 64 + nn * 16 + l15;
      const float sqc = sq[gc];
#pragma unroll
      for (int rg = 0; rg < 4; ++rg) {
        const int gr = gr0 + rg;
        float d2 = fmaxf(sq[gr] + sqc - 2.0f * acc[m][nn][rg], 0.0f);
        pdh[(size_t)gr * b + gc] = __float2half((gr == gc) ? INFV : d2);
      }
    }
  }
}

// ---------- kernel 3: wave-per-row top-16 select (shuffle-only), exact re-rank, loss ----------
// Requires b == 4096 (64 chunks of 64 lanes), d == 512, C == 128.
__global__ __launch_bounds__(256)
void topk_loss_kernel(const __half* __restrict__ pdh,
                      const float* __restrict__ zi, const float* __restrict__ zj,
                      const float* __restrict__ pi, const float* __restrict__ pj,
                      const int* __restrict__ labels,
                      const float* __restrict__ sq,
                      float* __restrict__ rowsum,
                      int n, int d, int C, int b) {
  const int t = threadIdx.x, lane = t & 63, wave = t >> 6;
  const int row = blockIdx.x * 4 + wave;

  // ---- Phase A: load row of packed (fp16 d2, idx); top-16 by repeated wave argmin ----
  const ushort8* rowp = (const ushort8*)(pdh + (size_t)row * b);
  unsigned vv[8][8];
  unsigned cmin[8];
#pragma unroll
  for (int ch = 0; ch < 8; ++ch) {
    ushort8 h = rowp[ch * 64 + lane];
    unsigned mn = 0xFFFFFFFFu;
#pragma unroll
    for (int j = 0; j < 8; ++j) {
      unsigned pk = ((unsigned)h[j] << 16) | (unsigned)(ch * 512 + lane * 8 + j);
      vv[ch][j] = pk;
      mn = min(mn, pk);
    }
    cmin[ch] = mn;
  }

  int c[NC];
#pragma unroll
  for (int r = 0; r < NC; ++r) {
    unsigned best = cmin[0];
#pragma unroll
    for (int ch = 1; ch < 8; ++ch) best = min(best, cmin[ch]);
#pragma unroll
    for (int o = 32; o; o >>= 1) {
      unsigned q = __shfl_xor(best, o, 64);
      best = min(best, q);
    }
    const int idx = (int)(best & 0xFFFFu);
    c[r] = idx;
    if (((idx >> 3) & 63) == lane) {       // owner invalidates + rebuilds its chunk-min
      const int ch = idx >> 9, jj = idx & 7;
#pragma unroll
      for (int cc = 0; cc < 8; ++cc) {
        if (cc == ch) {
          unsigned mn = 0xFFFFFFFFu;
#pragma unroll
          for (int j = 0; j < 8; ++j) {
            if (j == jj) vv[cc][j] = 0xFFFFFFFFu;
            mn = min(mn, vv[cc][j]);
          }
          cmin[cc] = mn;
        }
      }
    }
  }

  // ---- Phase B: exact fp32 d2 for the 16 candidates (my row in 8 VGPRs) ----
  const float* fme = (row < n) ? (zi + (size_t)row * d) : (zj + (size_t)(row - n) * d);
  float fr[8];
#pragma unroll
  for (int q = 0; q < 8; ++q) fr[q] = fme[lane + 64 * q];
  const float sqr = sq[row];

  float p[NC];
#pragma unroll
  for (int k = 0; k < NC; ++k) {
    const int j = c[k];
    const float* g = (j < n) ? (zi + (size_t)j * d) : (zj + (size_t)(j - n) * d);
    float part = 0.f;
#pragma unroll
    for (int q = 0; q < 8; ++q) part += fr[q] * g[lane + 64 * q];
#pragma unroll
    for (int o = 32; o; o >>= 1) part += __shfl_xor(part, o, 64);
    const float d2 = sqr + sq[j] - 2.0f * part;
    p[k] = sqrtf(fmaxf(d2, 0.0f));
  }

  // ---- Phase C: radius + branchless pairwise ranks (all compile-time indices) ----
  float r0 = p[0];
#pragma unroll
  for (int k = 1; k < NC; ++k) r0 = fminf(r0, p[k]);

  int rank[NC];
#pragma unroll
  for (int k = 0; k < NC; ++k) rank[k] = 0;
#pragma unroll
  for (int k = 1; k < NC; ++k) {
#pragma unroll
    for (int j = 0; j < k; ++j) {
      const bool tt = p[j] <= p[k];   // tie -> earlier extraction wins (lower approx (d2,idx))
      rank[k] += tt ? 1 : 0;
      rank[j] += tt ? 0 : 1;
    }
  }

  // ---- Phase D: masked contributions; prob dot only when mask passes (wave-uniform) ----
  const int ri = (row < n) ? row : row - n;
  const int li = labels[ri];
  const float* pme = (row < n) ? (pi + (size_t)row * C) : (pj + (size_t)(row - n) * C);
  const float pr0 = pme[lane], pr1 = pme[lane + 64];

  float tot = 0.f;
#pragma unroll
  for (int k = 0; k < NC; ++k) {
    const int j = c[k];
    const int rj = (j < n) ? j : j - n;
    const int lj = labels[rj];
    const bool m = (rank[k] < 10) & (li != -1) & (lj != -1) & (li == lj) & (ri != rj);
    if (m) {   // identical across lanes -> uniform branch
      const float* q = (j < n) ? (pi + (size_t)j * C) : (pj + (size_t)(j - n) * C);
      float part = pr0 * q[lane] + pr1 * q[lane + 64];
#pragma unroll
      for (int o = 32; o; o >>= 1) part += __shfl_xor(part, o, 64);
      const float w = 1.0f - fminf(fmaxf((p[k] - r0) / r0, 0.0f), 1.0f);
      tot += w * part;
    }
  }
  if (lane == 0) rowsum[row] = tot;
}

// ---------- kernel 4: deterministic final reduce ----------
__global__ __launch_bounds__(256)
void final_reduce_kernel(const float* __restrict__ rowsum, float* __restrict__ out, int b) {
  __shared__ float wredf[4];
  const int t = threadIdx.x, lane = t & 63, wave = t >> 6;
  float s = 0.f;
  for (int c = t; c < b; c += 256) s += rowsum[c];
#pragma unroll
  for (int o = 32; o; o >>= 1) s += __shfl_xor(s, o, 64);
  if (lane == 0) wredf[wave] = s;
  __syncthreads();
  if (t == 0) {
    float tot = ((wredf[0] + wredf[1]) + wredf[2]) + wredf[3];
    out[0] = tot / ((float)b * (float)b);
  }
}

extern "C" void kernel_launch(void* const* d_in, const int* in_sizes, int n_in,
                              void* d_out, int out_size, void* d_ws, size_t ws_size,
                              hipStream_t stream) {
  const float* zi = (const float*)d_in[0];
  const float* zj = (const float*)d_in[1];
  const float* pi = (const float*)d_in[2];
  const float* pj = (const float*)d_in[3];
  const int* labels = (const int*)d_in[4];

  const int n = in_sizes[4];          // 2048
  const int d = in_sizes[0] / n;      // 512
  const int C = in_sizes[2] / n;      // 128
  const int b = 2 * n;                // 4096

  char* ws = (char*)d_ws;
  size_t off = 0;
  unsigned short* fb = (unsigned short*)(ws + off);
  off += ((size_t)b * d * 2 + 255) & ~(size_t)255;
  float* sq = (float*)(ws + off);
  off += ((size_t)b * 4 + 255) & ~(size_t)255;
  float* rowsum = (float*)(ws + off);
  off += ((size_t)b * 4 + 255) & ~(size_t)255;
  __half* pdh = (__half*)(ws + off);
  off += (size_t)b * b * 2;
  if (ws_size < off) return;  // workspace too small — bail rather than corrupt

  prep_kernel<<<b, 256, 0, stream>>>(zi, zj, fb, sq, n, d);
  dim3 grid(b / BN, b / BM);
  gemm_pd_kernel<<<grid, 256, 0, stream>>>(fb, sq, pdh, b, d);
  topk_loss_kernel<<<b / 4, 256, 0, stream>>>(pdh, zi, zj, pi, pj, labels, sq, rowsum, n, d, C, b);
  final_reduce_kernel<<<1, 256, 0, stream>>>(rowsum, (float*)d_out, b);
}